// Round 1
// baseline (26749.536 us; speedup 1.0000x reference)
//
#include <hip/hip_runtime.h>
#include <stdint.h>

#define NB 64
#define NT 512
#define NH 512

typedef short bf8 __attribute__((ext_vector_type(8)));   // 8 bf16 vals (4 VGPRs)
typedef float f4  __attribute__((ext_vector_type(4)));

static __device__ __forceinline__ float bf2f(uint16_t u) {
  union { uint32_t i; float f; } v; v.i = ((uint32_t)u) << 16; return v.f;
}
static __device__ __forceinline__ uint16_t f2bf(float f) {
  union { float f; uint32_t i; } v; v.f = f;
  uint32_t r = v.i + 0x7fffu + ((v.i >> 16) & 1u);
  return (uint16_t)(r >> 16);
}

__global__ void k_f2bf(const float* __restrict__ src, uint16_t* __restrict__ dst, int n4) {
  int i = blockIdx.x * 256 + threadIdx.x;
  if (i < n4) {
    float4 v = ((const float4*)src)[i];
    uint16_t* d = dst + (size_t)i * 4;
    d[0] = f2bf(v.x); d[1] = f2bf(v.y); d[2] = f2bf(v.z); d[3] = f2bf(v.w);
  }
}

// rows permuted: row' = u*4+gate  <-  row = gate*512 + u ; fp32 -> bf16
__global__ void k_wperm(const float* __restrict__ src, uint16_t* __restrict__ dst, int K) {
  int rp = blockIdx.x;
  int row = (rp & 3) * NH + (rp >> 2);
  const float* s = src + (size_t)row * K;
  uint16_t* d = dst + (size_t)rp * K;
  for (int k = threadIdx.x; k < K; k += 256) d[k] = f2bf(s[k]);
}

__global__ void k_bperm(const float* __restrict__ src, float* __restrict__ dst) {
  int rp = blockIdx.x * 256 + threadIdx.x;
  if (rp < 2048) {
    int row = (rp & 3) * NH + (rp >> 2);
    dst[rp] = src[row];
  }
}

// C[m=b*T+t][n] = A[m][:] . W[n][:]  + bias[n], written bf16 to xg[t][b][n&2047]
// A: bf16 [32768][K], W: bf16 [4096][K] (rows: dir f = 0..2047, dir b = 2048..4095)
template<int K>
__global__ __launch_bounds__(256, 2)
void k_gemm(const uint16_t* __restrict__ A, const uint16_t* __restrict__ W,
            const float* __restrict__ bias,
            uint16_t* __restrict__ xg_f, uint16_t* __restrict__ xg_b) {
  __shared__ __align__(16) uint16_t lds[2][2][8][512];   // [buf][A/B][tile][frag slots] 32 KB
  const int tid = threadIdx.x;
  const int w = tid >> 6, lane = tid & 63;
  const int quad = lane >> 4, nIdx = lane & 15;
  const int bn = blockIdx.x, bm = blockIdx.y;
  const int wm = w >> 1, wn = w & 1;
  constexpr int KS = K / 32;

  f4 acc[4][4];
  #pragma unroll
  for (int i = 0; i < 4; ++i)
    #pragma unroll
    for (int j = 0; j < 4; ++j)
      #pragma unroll
      for (int q = 0; q < 4; ++q) acc[i][j][q] = 0.f;

  const size_t arow0 = (size_t)(bm * 128 + nIdx) * K + quad * 8;
  const size_t brow0 = (size_t)(bn * 128 + nIdx) * K + quad * 8;

  #pragma unroll
  for (int cc = 0; cc < 2; ++cc) {   // preload ks=0 into buf0
    int mt = w + cc * 4;
    bf8 va = *(const bf8*)(A + arow0 + (size_t)mt * 16 * K);
    bf8 vb = *(const bf8*)(W + brow0 + (size_t)mt * 16 * K);
    *(bf8*)&lds[0][0][mt][lane * 8] = va;
    *(bf8*)&lds[0][1][mt][lane * 8] = vb;
  }
  for (int ks = 0; ks < KS; ++ks) {
    __syncthreads();
    bf8 va[2], vb[2];
    const bool pre = (ks + 1 < KS);
    if (pre) {
      #pragma unroll
      for (int cc = 0; cc < 2; ++cc) {
        int mt = w + cc * 4;
        va[cc] = *(const bf8*)(A + arow0 + (size_t)mt * 16 * K + (ks + 1) * 32);
        vb[cc] = *(const bf8*)(W + brow0 + (size_t)mt * 16 * K + (ks + 1) * 32);
      }
    }
    const int buf = ks & 1;
    bf8 af[4], bg[4];
    #pragma unroll
    for (int i = 0; i < 4; ++i) af[i] = *(const bf8*)&lds[buf][0][wm * 4 + i][lane * 8];
    #pragma unroll
    for (int j = 0; j < 4; ++j) bg[j] = *(const bf8*)&lds[buf][1][wn * 4 + j][lane * 8];
    #pragma unroll
    for (int i = 0; i < 4; ++i)
      #pragma unroll
      for (int j = 0; j < 4; ++j)
        acc[i][j] = __builtin_amdgcn_mfma_f32_16x16x32_bf16(af[i], bg[j], acc[i][j], 0, 0, 0);
    if (pre) {
      #pragma unroll
      for (int cc = 0; cc < 2; ++cc) {
        int mt = w + cc * 4;
        *(bf8*)&lds[buf ^ 1][0][mt][lane * 8] = va[cc];
        *(bf8*)&lds[buf ^ 1][1][mt][lane * 8] = vb[cc];
      }
    }
  }
  #pragma unroll
  for (int i = 0; i < 4; ++i) {
    int mbase = bm * 128 + (wm * 4 + i) * 16 + quad * 4;
    #pragma unroll
    for (int r = 0; r < 4; ++r) {
      int mm = mbase + r;
      int bb = mm >> 9, tt = mm & 511;
      size_t rowoff = ((size_t)tt * 64 + bb) * 2048;
      #pragma unroll
      for (int j = 0; j < 4; ++j) {
        int n = bn * 128 + (wn * 4 + j) * 16 + nIdx;
        float v = acc[i][j][r] + bias[n];
        uint16_t* dst = (n < 2048) ? xg_f : xg_b;
        dst[rowoff + (n & 2047)] = f2bf(v);
      }
    }
  }
}

// Persistent recurrence. grid = 64 blocks: dir = blk>>5, wg = blk&31 owns gate-rows'
// [wg*64, wg*64+64) = hidden [wg*16, wg*16+16) x 4 interleaved gates.
// Wave w (of 4): rows' wg*64+w*16+lane&15; all 64 batches (4 m-tiles).
// Wh fragments persist in VGPRs; c/h state in registers; h exchanged via global dbuf + ctr barrier.
template<bool FINAL>
__global__ __launch_bounds__(256, 1)
void k_recur(const uint16_t* __restrict__ xg_f, const uint16_t* __restrict__ xg_b,
             const uint16_t* __restrict__ WhP, const int* __restrict__ lens,
             uint16_t* __restrict__ hbuf, int* __restrict__ ctr,
             uint16_t* __restrict__ y0, float* __restrict__ dout, int layer) {
  const int tid = threadIdx.x;
  const int w = tid >> 6, lane = tid & 63;
  const int quad = lane >> 4, nIdx = lane & 15;
  const int dir = blockIdx.x >> 5, wg = blockIdx.x & 31;
  const int rowp = wg * 64 + w * 16 + nIdx;
  const int gate = rowp & 3;
  const int u = rowp >> 2;
  const uint16_t* xg = dir ? xg_b : xg_f;
  const uint16_t* Wrow = WhP + ((size_t)dir * 2048 + rowp) * 512;
  bf8 bfr[16];
  #pragma unroll
  for (int kt = 0; kt < 16; ++kt) bfr[kt] = *(const bf8*)(Wrow + kt * 32 + quad * 8);
  float c[16], h[16];
  int len[16];
  #pragma unroll
  for (int si = 0; si < 16; ++si) { c[si] = 0.f; h[si] = 0.f; }
  #pragma unroll
  for (int mt = 0; mt < 4; ++mt)
    #pragma unroll
    for (int r = 0; r < 4; ++r) len[mt * 4 + r] = lens[mt * 16 + quad * 4 + r];
  int* myctr = ctr + dir * 512;
  uint16_t* hb = hbuf + (size_t)dir * 2 * NB * NH;

  for (int s = 0; s < 512; ++s) {
    const int t = dir ? (511 - s) : s;
    f4 acc[4];
    #pragma unroll
    for (int mt = 0; mt < 4; ++mt)
      #pragma unroll
      for (int q = 0; q < 4; ++q) acc[mt][q] = 0.f;
    if (s > 0) {
      if (tid == 0) {
        while (__hip_atomic_load(myctr + (s - 1), __ATOMIC_RELAXED, __HIP_MEMORY_SCOPE_AGENT) < 32)
          __builtin_amdgcn_s_sleep(1);
      }
      __syncthreads();
      __threadfence();   // acquire: see other WGs' h writes
      const uint16_t* hr = hb + ((s + 1) & 1) * (NB * NH);
      #pragma unroll
      for (int mt = 0; mt < 4; ++mt) {
        const uint16_t* hrow = hr + (size_t)(mt * 16 + nIdx) * NH + quad * 8;
        #pragma unroll
        for (int kt = 0; kt < 16; ++kt)
          acc[mt] = __builtin_amdgcn_mfma_f32_16x16x32_bf16(
              *(const bf8*)(hrow + kt * 32), bfr[kt], acc[mt], 0, 0, 0);
      }
    }
    uint16_t* hw = hb + (s & 1) * (NB * NH);
    #pragma unroll
    for (int mt = 0; mt < 4; ++mt) {
      #pragma unroll
      for (int r = 0; r < 4; ++r) {
        const int si = mt * 4 + r;
        const int bb = mt * 16 + quad * 4 + r;
        float g = acc[mt][r] + bf2f(xg[((size_t)t * 64 + bb) * 2048 + rowp]);
        float act;
        if (gate == 2) { float e = __expf(2.f * g); act = 1.f - 2.f / (e + 1.f); }
        else           { act = 1.f / (1.f + __expf(-g)); }
        float a1 = __shfl_xor(act, 1, 64);
        float a2 = __shfl_xor(act, 2, 64);
        float a3 = __shfl_xor(act, 3, 64);
        float vi = (gate == 0) ? act : ((gate == 1) ? a1 : ((gate == 2) ? a2 : a3));
        float vf = (gate == 1) ? act : ((gate == 0) ? a1 : ((gate == 3) ? a2 : a3));
        float vg = (gate == 2) ? act : ((gate == 3) ? a1 : ((gate == 0) ? a2 : a3));
        float vo = (gate == 3) ? act : ((gate == 2) ? a1 : ((gate == 1) ? a2 : a3));
        float cn = vf * c[si] + vi * vg;
        float e2 = __expf(2.f * cn);
        float th = 1.f - 2.f / (e2 + 1.f);
        float hn = vo * th;
        bool valid = (t < len[si]);
        float cnew = valid ? cn : c[si];
        float hnew = valid ? hn : h[si];
        c[si] = cnew; h[si] = hnew;
        if (gate == 1) hw[(size_t)bb * NH + u] = f2bf(hnew);
        if (gate == 0) {
          float yv = valid ? hn : 0.f;
          size_t yo = ((size_t)bb * 512 + t) * 1024 + (size_t)dir * 512 + u;
          if (FINAL) dout[yo] = yv; else y0[yo] = f2bf(yv);
        }
      }
    }
    __syncthreads();                       // all waves' stores drained (vmcnt 0 at barrier)
    if (tid == 0) { __threadfence(); atomicAdd(myctr + s, 1); }   // release + arrive
  }
  if (gate == 2) {
    const size_t HN = 33554432, CN = 33554432 + 131072;
    int slot = layer * 2 + dir;
    #pragma unroll
    for (int mt = 0; mt < 4; ++mt)
      #pragma unroll
      for (int r = 0; r < 4; ++r) {
        int bb = mt * 16 + quad * 4 + r;
        dout[HN + ((size_t)slot * 64 + bb) * 512 + u] = h[mt * 4 + r];
        dout[CN + ((size_t)slot * 64 + bb) * 512 + u] = c[mt * 4 + r];
      }
  }
}

extern "C" void kernel_launch(void* const* d_in, const int* in_sizes, int n_in,
                              void* d_out, int out_size, void* d_ws, size_t ws_size,
                              hipStream_t stream) {
  (void)in_sizes; (void)n_in; (void)out_size; (void)ws_size;
  const float* x     = (const float*)d_in[0];
  const int*   lens  = (const int*)d_in[1];
  const float* Wi_f0 = (const float*)d_in[2];
  const float* Wh_f0 = (const float*)d_in[3];
  const float* b_f0  = (const float*)d_in[4];
  const float* Wi_b0 = (const float*)d_in[5];
  const float* Wh_b0 = (const float*)d_in[6];
  const float* b_b0  = (const float*)d_in[7];
  const float* Wi_f1 = (const float*)d_in[8];
  const float* Wh_f1 = (const float*)d_in[9];
  const float* b_f1  = (const float*)d_in[10];
  const float* Wi_b1 = (const float*)d_in[11];
  const float* Wh_b1 = (const float*)d_in[12];
  const float* b_b1  = (const float*)d_in[13];
  float* out = (float*)d_out;
  char* ws = (char*)d_ws;

  const size_t CTR = 0;                       // int[2][2][512] = 8 KB
  const size_t BIAS0 = 8192, BIAS1 = 24576;   // fp32 [4096] each
  const size_t HBUF = 40960;                  // bf16 [2][2][64][512] = 256 KB
  const size_t XBF   = 303104;                // bf16 x: 32 MB
  const size_t Y0    = XBF + 33554432;        // bf16 y0 [64][512][1024]: 64 MB
  const size_t WCAT0 = Y0 + 67108864;         // bf16 [4096][512]
  const size_t WCAT1 = WCAT0 + 4194304;       // bf16 [4096][1024]
  const size_t WHP0  = WCAT1 + 8388608;       // bf16 [2][2048][512]
  const size_t WHP1  = WHP0 + 4194304;
  const size_t XGF   = WHP1 + 4194304;        // bf16 [512][64][2048]: 128 MB
  const size_t XGB   = XGF + 134217728;       // 128 MB  (total ~372 MB)

  int* ctr        = (int*)(ws + CTR);
  float* bias0    = (float*)(ws + BIAS0);
  float* bias1    = (float*)(ws + BIAS1);
  uint16_t* hbuf  = (uint16_t*)(ws + HBUF);
  uint16_t* xbf   = (uint16_t*)(ws + XBF);
  uint16_t* y0    = (uint16_t*)(ws + Y0);
  uint16_t* wcat0 = (uint16_t*)(ws + WCAT0);
  uint16_t* wcat1 = (uint16_t*)(ws + WCAT1);
  uint16_t* whp0  = (uint16_t*)(ws + WHP0);
  uint16_t* whp1  = (uint16_t*)(ws + WHP1);
  uint16_t* xgf   = (uint16_t*)(ws + XGF);
  uint16_t* xgb   = (uint16_t*)(ws + XGB);

  hipMemsetAsync(ws + CTR, 0, 8192, stream);
  k_f2bf<<<16384, 256, 0, stream>>>(x, xbf, 4194304);
  k_wperm<<<2048, 256, 0, stream>>>(Wi_f0, wcat0, 512);
  k_wperm<<<2048, 256, 0, stream>>>(Wi_b0, wcat0 + 2048 * 512, 512);
  k_wperm<<<2048, 256, 0, stream>>>(Wi_f1, wcat1, 1024);
  k_wperm<<<2048, 256, 0, stream>>>(Wi_b1, wcat1 + (size_t)2048 * 1024, 1024);
  k_wperm<<<2048, 256, 0, stream>>>(Wh_f0, whp0, 512);
  k_wperm<<<2048, 256, 0, stream>>>(Wh_b0, whp0 + 2048 * 512, 512);
  k_wperm<<<2048, 256, 0, stream>>>(Wh_f1, whp1, 512);
  k_wperm<<<2048, 256, 0, stream>>>(Wh_b1, whp1 + 2048 * 512, 512);
  k_bperm<<<8, 256, 0, stream>>>(b_f0, bias0);
  k_bperm<<<8, 256, 0, stream>>>(b_b0, bias0 + 2048);
  k_bperm<<<8, 256, 0, stream>>>(b_f1, bias1);
  k_bperm<<<8, 256, 0, stream>>>(b_b1, bias1 + 2048);

  k_gemm<512><<<dim3(32, 256), 256, 0, stream>>>(xbf, wcat0, bias0, xgf, xgb);
  k_recur<false><<<64, 256, 0, stream>>>(xgf, xgb, whp0, lens, hbuf, ctr, y0, out, 0);
  k_gemm<1024><<<dim3(32, 256), 256, 0, stream>>>(y0, wcat1, bias1, xgf, xgb);
  k_recur<true><<<64, 256, 0, stream>>>(xgf, xgb, whp1, lens, hbuf, ctr + 1024, y0, out, 1);
}

// Round 2
// 12129.707 us; speedup vs baseline: 2.2053x; 2.2053x over previous
//
#include <hip/hip_runtime.h>
#include <stdint.h>

#define NB 64
#define NT 512
#define NH 512

typedef short bf8 __attribute__((ext_vector_type(8)));   // 8 bf16 vals (4 VGPRs)
typedef float f4  __attribute__((ext_vector_type(4)));

static __device__ __forceinline__ float bf2f(uint16_t u) {
  union { uint32_t i; float f; } v; v.i = ((uint32_t)u) << 16; return v.f;
}
static __device__ __forceinline__ uint16_t f2bf(float f) {
  union { float f; uint32_t i; } v; v.f = f;
  uint32_t r = v.i + 0x7fffu + ((v.i >> 16) & 1u);
  return (uint16_t)(r >> 16);
}

__global__ void k_f2bf(const float* __restrict__ src, uint16_t* __restrict__ dst, int n4) {
  int i = blockIdx.x * 256 + threadIdx.x;
  if (i < n4) {
    float4 v = ((const float4*)src)[i];
    uint16_t* d = dst + (size_t)i * 4;
    d[0] = f2bf(v.x); d[1] = f2bf(v.y); d[2] = f2bf(v.z); d[3] = f2bf(v.w);
  }
}

// rows permuted: row' = u*4+gate  <-  row = gate*512 + u ; fp32 -> bf16
__global__ void k_wperm(const float* __restrict__ src, uint16_t* __restrict__ dst, int K) {
  int rp = blockIdx.x;
  int row = (rp & 3) * NH + (rp >> 2);
  const float* s = src + (size_t)row * K;
  uint16_t* d = dst + (size_t)rp * K;
  for (int k = threadIdx.x; k < K; k += 256) d[k] = f2bf(s[k]);
}

__global__ void k_bperm(const float* __restrict__ src, float* __restrict__ dst) {
  int rp = blockIdx.x * 256 + threadIdx.x;
  if (rp < 2048) {
    int row = (rp & 3) * NH + (rp >> 2);
    dst[rp] = src[row];
  }
}

// C[m=b*T+t][n] = A[m][:] . W[n][:]  + bias[n], written bf16 to xg[t][b][n&2047]
template<int K>
__global__ __launch_bounds__(256, 2)
void k_gemm(const uint16_t* __restrict__ A, const uint16_t* __restrict__ W,
            const float* __restrict__ bias,
            uint16_t* __restrict__ xg_f, uint16_t* __restrict__ xg_b) {
  __shared__ __align__(16) uint16_t lds[2][2][8][512];   // 32 KB
  const int tid = threadIdx.x;
  const int w = tid >> 6, lane = tid & 63;
  const int quad = lane >> 4, nIdx = lane & 15;
  const int bn = blockIdx.x, bm = blockIdx.y;
  const int wm = w >> 1, wn = w & 1;
  constexpr int KS = K / 32;

  f4 acc[4][4];
  #pragma unroll
  for (int i = 0; i < 4; ++i)
    #pragma unroll
    for (int j = 0; j < 4; ++j)
      #pragma unroll
      for (int q = 0; q < 4; ++q) acc[i][j][q] = 0.f;

  const size_t arow0 = (size_t)(bm * 128 + nIdx) * K + quad * 8;
  const size_t brow0 = (size_t)(bn * 128 + nIdx) * K + quad * 8;

  #pragma unroll
  for (int cc = 0; cc < 2; ++cc) {
    int mt = w + cc * 4;
    bf8 va = *(const bf8*)(A + arow0 + (size_t)mt * 16 * K);
    bf8 vb = *(const bf8*)(W + brow0 + (size_t)mt * 16 * K);
    *(bf8*)&lds[0][0][mt][lane * 8] = va;
    *(bf8*)&lds[0][1][mt][lane * 8] = vb;
  }
  for (int ks = 0; ks < KS; ++ks) {
    __syncthreads();
    bf8 va[2], vb[2];
    const bool pre = (ks + 1 < KS);
    if (pre) {
      #pragma unroll
      for (int cc = 0; cc < 2; ++cc) {
        int mt = w + cc * 4;
        va[cc] = *(const bf8*)(A + arow0 + (size_t)mt * 16 * K + (ks + 1) * 32);
        vb[cc] = *(const bf8*)(W + brow0 + (size_t)mt * 16 * K + (ks + 1) * 32);
      }
    }
    const int buf = ks & 1;
    bf8 af[4], bg[4];
    #pragma unroll
    for (int i = 0; i < 4; ++i) af[i] = *(const bf8*)&lds[buf][0][wm * 4 + i][lane * 8];
    #pragma unroll
    for (int j = 0; j < 4; ++j) bg[j] = *(const bf8*)&lds[buf][1][wn * 4 + j][lane * 8];
    #pragma unroll
    for (int i = 0; i < 4; ++i)
      #pragma unroll
      for (int j = 0; j < 4; ++j)
        acc[i][j] = __builtin_amdgcn_mfma_f32_16x16x32_bf16(af[i], bg[j], acc[i][j], 0, 0, 0);
    if (pre) {
      #pragma unroll
      for (int cc = 0; cc < 2; ++cc) {
        int mt = w + cc * 4;
        *(bf8*)&lds[buf ^ 1][0][mt][lane * 8] = va[cc];
        *(bf8*)&lds[buf ^ 1][1][mt][lane * 8] = vb[cc];
      }
    }
  }
  #pragma unroll
  for (int i = 0; i < 4; ++i) {
    int mbase = bm * 128 + (wm * 4 + i) * 16 + quad * 4;
    #pragma unroll
    for (int r = 0; r < 4; ++r) {
      int mm = mbase + r;
      int bb = mm >> 9, tt = mm & 511;
      size_t rowoff = ((size_t)tt * 64 + bb) * 2048;
      #pragma unroll
      for (int j = 0; j < 4; ++j) {
        int n = bn * 128 + (wn * 4 + j) * 16 + nIdx;
        float v = acc[i][j][r] + bias[n];
        uint16_t* dst = (n < 2048) ? xg_f : xg_b;
        dst[rowoff + (n & 2047)] = f2bf(v);
      }
    }
  }
}

// Persistent recurrence. grid = 64 blocks: dir = blk>>5, wg = blk&31 owns
// rows' [wg*64, wg*64+64). Wave w: rows' wg*64+w*16+nIdx, all 64 batches.
// h staged per-step into padded LDS (global traffic 1x per WG, max-MLP
// coalesced loads); xg prefetched into regs during the barrier window;
// directed acquire/release fences instead of full threadfence.
template<bool FINAL>
__global__ __launch_bounds__(256, 1)
void k_recur(const uint16_t* __restrict__ xg_f, const uint16_t* __restrict__ xg_b,
             const uint16_t* __restrict__ WhP, const int* __restrict__ lens,
             uint16_t* __restrict__ hbuf, int* __restrict__ ctr,
             uint16_t* __restrict__ y0, float* __restrict__ dout, int layer) {
  __shared__ __align__(16) uint16_t hlds[64 * 520];   // 64 rows x (512+8) u16 = 65 KB
  const int tid = threadIdx.x;
  const int w = tid >> 6, lane = tid & 63;
  const int quad = lane >> 4, nIdx = lane & 15;
  const int dir = blockIdx.x >> 5, wg = blockIdx.x & 31;
  const int rowp = wg * 64 + w * 16 + nIdx;
  const int gate = rowp & 3;
  const int u = rowp >> 2;
  const uint16_t* xg = dir ? xg_b : xg_f;
  const uint16_t* Wrow = WhP + ((size_t)dir * 2048 + rowp) * 512;
  bf8 bfr[16];
  #pragma unroll
  for (int kt = 0; kt < 16; ++kt) bfr[kt] = *(const bf8*)(Wrow + kt * 32 + quad * 8);
  float c[16], h[16];
  int len[16];
  #pragma unroll
  for (int si = 0; si < 16; ++si) { c[si] = 0.f; h[si] = 0.f; }
  #pragma unroll
  for (int mt = 0; mt < 4; ++mt)
    #pragma unroll
    for (int r = 0; r < 4; ++r) len[mt * 4 + r] = lens[mt * 16 + quad * 4 + r];
  int* myctr = ctr + dir * 512;
  uint16_t* hb = hbuf + (size_t)dir * 2 * NB * NH;

  // prefetch xg for step 0
  uint16_t xgp[16];
  {
    const int t0 = dir ? 511 : 0;
    #pragma unroll
    for (int mt = 0; mt < 4; ++mt)
      #pragma unroll
      for (int r = 0; r < 4; ++r) {
        const int bb = mt * 16 + quad * 4 + r;
        xgp[mt * 4 + r] = xg[((size_t)t0 * 64 + bb) * 2048 + rowp];
      }
  }

  for (int s = 0; s < 512; ++s) {
    const int t = dir ? (511 - s) : s;
    f4 acc[4];
    #pragma unroll
    for (int mt = 0; mt < 4; ++mt)
      #pragma unroll
      for (int q = 0; q < 4; ++q) acc[mt][q] = 0.f;
    if (s > 0) {
      if (tid == 0) {
        while (__hip_atomic_load(myctr + (s - 1), __ATOMIC_RELAXED, __HIP_MEMORY_SCOPE_AGENT) < 32)
          __builtin_amdgcn_s_sleep(1);
      }
      __syncthreads();
      __builtin_amdgcn_fence(__ATOMIC_ACQUIRE, "agent");   // inv L1/L2: see other XCDs' h
      // ---- stage h (64x512 bf16) into padded LDS, coalesced max-MLP ----
      const uint16_t* hr = hb + ((s + 1) & 1) * (NB * NH);
      bf8 tmp[16];
      #pragma unroll
      for (int i = 0; i < 16; ++i) {
        const int chunk = i * 256 + tid;                  // 4096 x 16B
        tmp[i] = *(const bf8*)(hr + (chunk >> 6) * 512 + (chunk & 63) * 8);
      }
      #pragma unroll
      for (int i = 0; i < 16; ++i) {
        const int chunk = i * 256 + tid;
        *(bf8*)&hlds[(chunk >> 6) * 520 + (chunk & 63) * 8] = tmp[i];
      }
      __syncthreads();
      // ---- MFMA from LDS ----
      #pragma unroll
      for (int mt = 0; mt < 4; ++mt) {
        const uint16_t* hrow = &hlds[(mt * 16 + nIdx) * 520 + quad * 8];
        #pragma unroll
        for (int kt = 0; kt < 16; ++kt)
          acc[mt] = __builtin_amdgcn_mfma_f32_16x16x32_bf16(
              *(const bf8*)(hrow + kt * 32), bfr[kt], acc[mt], 0, 0, 0);
      }
    }
    uint16_t* hw = hb + (s & 1) * (NB * NH);
    #pragma unroll
    for (int mt = 0; mt < 4; ++mt) {
      #pragma unroll
      for (int r = 0; r < 4; ++r) {
        const int si = mt * 4 + r;
        const int bb = mt * 16 + quad * 4 + r;
        float g = acc[mt][r] + bf2f(xgp[si]);
        float act;
        if (gate == 2) { float e = __expf(2.f * g); act = 1.f - 2.f / (e + 1.f); }
        else           { act = 1.f / (1.f + __expf(-g)); }
        float a1 = __shfl_xor(act, 1, 64);
        float a2 = __shfl_xor(act, 2, 64);
        float a3 = __shfl_xor(act, 3, 64);
        float vi = (gate == 0) ? act : ((gate == 1) ? a1 : ((gate == 2) ? a2 : a3));
        float vf = (gate == 1) ? act : ((gate == 0) ? a1 : ((gate == 3) ? a2 : a3));
        float vg = (gate == 2) ? act : ((gate == 3) ? a1 : ((gate == 0) ? a2 : a3));
        float vo = (gate == 3) ? act : ((gate == 2) ? a1 : ((gate == 1) ? a2 : a3));
        float cn = vf * c[si] + vi * vg;
        float e2 = __expf(2.f * cn);
        float th = 1.f - 2.f / (e2 + 1.f);
        float hn = vo * th;
        bool valid = (t < len[si]);
        float cnew = valid ? cn : c[si];
        float hnew = valid ? hn : h[si];
        c[si] = cnew; h[si] = hnew;
        if (gate == 1) hw[(size_t)bb * NH + u] = f2bf(hnew);
        if (gate == 0) {
          float yv = valid ? hn : 0.f;
          size_t yo = ((size_t)bb * 512 + t) * 1024 + (size_t)dir * 512 + u;
          if (FINAL) __builtin_nontemporal_store(yv, &dout[yo]);
          else       __builtin_nontemporal_store(f2bf(yv), &y0[yo]);
        }
      }
    }
    __syncthreads();   // all waves' stores drained (vmcnt 0 at barrier)
    if (tid == 0) {
      __builtin_amdgcn_fence(__ATOMIC_RELEASE, "agent");   // wbl2: publish h
      atomicAdd(myctr + s, 1);
    }
    // ---- prefetch xg for next step during the barrier window ----
    {
      const int sp = (s + 1 < 512) ? (s + 1) : 511;
      const int t2 = dir ? (511 - sp) : sp;
      #pragma unroll
      for (int mt = 0; mt < 4; ++mt)
        #pragma unroll
        for (int r = 0; r < 4; ++r) {
          const int bb = mt * 16 + quad * 4 + r;
          xgp[mt * 4 + r] = xg[((size_t)t2 * 64 + bb) * 2048 + rowp];
        }
    }
  }
  if (gate == 2) {
    const size_t HN = 33554432, CN = 33554432 + 131072;
    int slot = layer * 2 + dir;
    #pragma unroll
    for (int mt = 0; mt < 4; ++mt)
      #pragma unroll
      for (int r = 0; r < 4; ++r) {
        int bb = mt * 16 + quad * 4 + r;
        dout[HN + ((size_t)slot * 64 + bb) * 512 + u] = h[mt * 4 + r];
        dout[CN + ((size_t)slot * 64 + bb) * 512 + u] = c[mt * 4 + r];
      }
  }
}

extern "C" void kernel_launch(void* const* d_in, const int* in_sizes, int n_in,
                              void* d_out, int out_size, void* d_ws, size_t ws_size,
                              hipStream_t stream) {
  (void)in_sizes; (void)n_in; (void)out_size; (void)ws_size;
  const float* x     = (const float*)d_in[0];
  const int*   lens  = (const int*)d_in[1];
  const float* Wi_f0 = (const float*)d_in[2];
  const float* Wh_f0 = (const float*)d_in[3];
  const float* b_f0  = (const float*)d_in[4];
  const float* Wi_b0 = (const float*)d_in[5];
  const float* Wh_b0 = (const float*)d_in[6];
  const float* b_b0  = (const float*)d_in[7];
  const float* Wi_f1 = (const float*)d_in[8];
  const float* Wh_f1 = (const float*)d_in[9];
  const float* b_f1  = (const float*)d_in[10];
  const float* Wi_b1 = (const float*)d_in[11];
  const float* Wh_b1 = (const float*)d_in[12];
  const float* b_b1  = (const float*)d_in[13];
  float* out = (float*)d_out;
  char* ws = (char*)d_ws;

  const size_t CTR = 0;                       // int[2][2][512] = 8 KB
  const size_t BIAS0 = 8192, BIAS1 = 24576;   // fp32 [4096] each
  const size_t HBUF = 40960;                  // bf16 [2][2][64][512] = 256 KB
  const size_t XBF   = 303104;                // bf16 x: 32 MB
  const size_t Y0    = XBF + 33554432;        // bf16 y0 [64][512][1024]: 64 MB
  const size_t WCAT0 = Y0 + 67108864;         // bf16 [4096][512]
  const size_t WCAT1 = WCAT0 + 4194304;       // bf16 [4096][1024]
  const size_t WHP0  = WCAT1 + 8388608;       // bf16 [2][2048][512]
  const size_t WHP1  = WHP0 + 4194304;
  const size_t XGF   = WHP1 + 4194304;        // bf16 [512][64][2048]: 128 MB
  const size_t XGB   = XGF + 134217728;       // 128 MB  (total ~372 MB)

  int* ctr        = (int*)(ws + CTR);
  float* bias0    = (float*)(ws + BIAS0);
  float* bias1    = (float*)(ws + BIAS1);
  uint16_t* hbuf  = (uint16_t*)(ws + HBUF);
  uint16_t* xbf   = (uint16_t*)(ws + XBF);
  uint16_t* y0    = (uint16_t*)(ws + Y0);
  uint16_t* wcat0 = (uint16_t*)(ws + WCAT0);
  uint16_t* wcat1 = (uint16_t*)(ws + WCAT1);
  uint16_t* whp0  = (uint16_t*)(ws + WHP0);
  uint16_t* whp1  = (uint16_t*)(ws + WHP1);
  uint16_t* xgf   = (uint16_t*)(ws + XGF);
  uint16_t* xgb   = (uint16_t*)(ws + XGB);

  hipMemsetAsync(ws + CTR, 0, 8192, stream);
  k_f2bf<<<16384, 256, 0, stream>>>(x, xbf, 4194304);
  k_wperm<<<2048, 256, 0, stream>>>(Wi_f0, wcat0, 512);
  k_wperm<<<2048, 256, 0, stream>>>(Wi_b0, wcat0 + 2048 * 512, 512);
  k_wperm<<<2048, 256, 0, stream>>>(Wi_f1, wcat1, 1024);
  k_wperm<<<2048, 256, 0, stream>>>(Wi_b1, wcat1 + (size_t)2048 * 1024, 1024);
  k_wperm<<<2048, 256, 0, stream>>>(Wh_f0, whp0, 512);
  k_wperm<<<2048, 256, 0, stream>>>(Wh_b0, whp0 + 2048 * 512, 512);
  k_wperm<<<2048, 256, 0, stream>>>(Wh_f1, whp1, 512);
  k_wperm<<<2048, 256, 0, stream>>>(Wh_b1, whp1 + 2048 * 512, 512);
  k_bperm<<<8, 256, 0, stream>>>(b_f0, bias0);
  k_bperm<<<8, 256, 0, stream>>>(b_b0, bias0 + 2048);
  k_bperm<<<8, 256, 0, stream>>>(b_f1, bias1);
  k_bperm<<<8, 256, 0, stream>>>(b_b1, bias1 + 2048);

  k_gemm<512><<<dim3(32, 256), 256, 0, stream>>>(xbf, wcat0, bias0, xgf, xgb);
  k_recur<false><<<64, 256, 0, stream>>>(xgf, xgb, whp0, lens, hbuf, ctr, y0, out, 0);
  k_gemm<1024><<<dim3(32, 256), 256, 0, stream>>>(y0, wcat1, bias1, xgf, xgb);
  k_recur<true><<<64, 256, 0, stream>>>(xgf, xgb, whp1, lens, hbuf, ctr + 1024, y0, out, 1);
}

// Round 3
// 8663.499 us; speedup vs baseline: 3.0876x; 1.4001x over previous
//
#include <hip/hip_runtime.h>
#include <stdint.h>

#define NB 64
#define NT 512
#define NH 512

typedef short bf8 __attribute__((ext_vector_type(8)));   // 8 bf16 vals (4 VGPRs)
typedef float f4  __attribute__((ext_vector_type(4)));

static __device__ __forceinline__ float bf2f(uint16_t u) {
  union { uint32_t i; float f; } v; v.i = ((uint32_t)u) << 16; return v.f;
}
static __device__ __forceinline__ uint16_t f2bf(float f) {
  union { float f; uint32_t i; } v; v.f = f;
  uint32_t r = v.i + 0x7fffu + ((v.i >> 16) & 1u);
  return (uint16_t)(r >> 16);
}

__global__ void k_f2bf(const float* __restrict__ src, uint16_t* __restrict__ dst, int n4) {
  int i = blockIdx.x * 256 + threadIdx.x;
  if (i < n4) {
    float4 v = ((const float4*)src)[i];
    uint16_t* d = dst + (size_t)i * 4;
    d[0] = f2bf(v.x); d[1] = f2bf(v.y); d[2] = f2bf(v.z); d[3] = f2bf(v.w);
  }
}

// rows permuted: row' = u*4+gate  <-  row = gate*512 + u ; fp32 -> bf16
__global__ void k_wperm(const float* __restrict__ src, uint16_t* __restrict__ dst, int K) {
  int rp = blockIdx.x;
  int row = (rp & 3) * NH + (rp >> 2);
  const float* s = src + (size_t)row * K;
  uint16_t* d = dst + (size_t)rp * K;
  for (int k = threadIdx.x; k < K; k += 256) d[k] = f2bf(s[k]);
}

__global__ void k_bperm(const float* __restrict__ src, float* __restrict__ dst) {
  int rp = blockIdx.x * 256 + threadIdx.x;
  if (rp < 2048) {
    int row = (rp & 3) * NH + (rp >> 2);
    dst[rp] = src[row];
  }
}

// C[m=b*T+t][n] = A[m][:] . W[n][:]  + bias[n], written bf16 to xg[t][b][n&2047]
template<int K>
__global__ __launch_bounds__(256, 2)
void k_gemm(const uint16_t* __restrict__ A, const uint16_t* __restrict__ W,
            const float* __restrict__ bias,
            uint16_t* __restrict__ xg_f, uint16_t* __restrict__ xg_b) {
  __shared__ __align__(16) uint16_t lds[2][2][8][512];   // 32 KB
  const int tid = threadIdx.x;
  const int w = tid >> 6, lane = tid & 63;
  const int quad = lane >> 4, nIdx = lane & 15;
  const int bn = blockIdx.x, bm = blockIdx.y;
  const int wm = w >> 1, wn = w & 1;
  constexpr int KS = K / 32;

  f4 acc[4][4];
  #pragma unroll
  for (int i = 0; i < 4; ++i)
    #pragma unroll
    for (int j = 0; j < 4; ++j)
      #pragma unroll
      for (int q = 0; q < 4; ++q) acc[i][j][q] = 0.f;

  const size_t arow0 = (size_t)(bm * 128 + nIdx) * K + quad * 8;
  const size_t brow0 = (size_t)(bn * 128 + nIdx) * K + quad * 8;

  #pragma unroll
  for (int cc = 0; cc < 2; ++cc) {
    int mt = w + cc * 4;
    bf8 va = *(const bf8*)(A + arow0 + (size_t)mt * 16 * K);
    bf8 vb = *(const bf8*)(W + brow0 + (size_t)mt * 16 * K);
    *(bf8*)&lds[0][0][mt][lane * 8] = va;
    *(bf8*)&lds[0][1][mt][lane * 8] = vb;
  }
  for (int ks = 0; ks < KS; ++ks) {
    __syncthreads();
    bf8 va[2], vb[2];
    const bool pre = (ks + 1 < KS);
    if (pre) {
      #pragma unroll
      for (int cc = 0; cc < 2; ++cc) {
        int mt = w + cc * 4;
        va[cc] = *(const bf8*)(A + arow0 + (size_t)mt * 16 * K + (ks + 1) * 32);
        vb[cc] = *(const bf8*)(W + brow0 + (size_t)mt * 16 * K + (ks + 1) * 32);
      }
    }
    const int buf = ks & 1;
    bf8 af[4], bg[4];
    #pragma unroll
    for (int i = 0; i < 4; ++i) af[i] = *(const bf8*)&lds[buf][0][wm * 4 + i][lane * 8];
    #pragma unroll
    for (int j = 0; j < 4; ++j) bg[j] = *(const bf8*)&lds[buf][1][wn * 4 + j][lane * 8];
    #pragma unroll
    for (int i = 0; i < 4; ++i)
      #pragma unroll
      for (int j = 0; j < 4; ++j)
        acc[i][j] = __builtin_amdgcn_mfma_f32_16x16x32_bf16(af[i], bg[j], acc[i][j], 0, 0, 0);
    if (pre) {
      #pragma unroll
      for (int cc = 0; cc < 2; ++cc) {
        int mt = w + cc * 4;
        *(bf8*)&lds[buf ^ 1][0][mt][lane * 8] = va[cc];
        *(bf8*)&lds[buf ^ 1][1][mt][lane * 8] = vb[cc];
      }
    }
  }
  #pragma unroll
  for (int i = 0; i < 4; ++i) {
    int mbase = bm * 128 + (wm * 4 + i) * 16 + quad * 4;
    #pragma unroll
    for (int r = 0; r < 4; ++r) {
      int mm = mbase + r;
      int bb = mm >> 9, tt = mm & 511;
      size_t rowoff = ((size_t)tt * 64 + bb) * 2048;
      #pragma unroll
      for (int j = 0; j < 4; ++j) {
        int n = bn * 128 + (wn * 4 + j) * 16 + nIdx;
        float v = acc[i][j][r] + bias[n];
        uint16_t* dst = (n < 2048) ? xg_f : xg_b;
        dst[rowoff + (n & 2047)] = f2bf(v);
      }
    }
  }
}

// Persistent recurrence. grid = 64 blocks: dir = blk>>5, wg = blk&31 owns
// rows' [wg*64, wg*64+64). Wave w: rows' wg*64+w*16+nIdx, all 64 batches.
// Coherence via targeted sc0/sc1 ops only (NO whole-L2 fences):
//  - h publish: scattered global_store_short sc0 sc1 (write-through to L3)
//  - arrival: vmcnt drain -> barrier -> relaxed atomicAdd (device scope, at L3)
//  - consume: relaxed agent poll -> barrier -> 16x global_load_dwordx4 sc0 sc1
template<bool FINAL>
__global__ __launch_bounds__(256, 1)
void k_recur(const uint16_t* __restrict__ xg_f, const uint16_t* __restrict__ xg_b,
             const uint16_t* __restrict__ WhP, const int* __restrict__ lens,
             uint16_t* __restrict__ hbuf, int* __restrict__ ctr,
             uint16_t* __restrict__ y0, float* __restrict__ dout, int layer) {
  __shared__ __align__(16) uint16_t hlds[64 * 520];   // 64 rows x (512+8) u16
  const int tid = threadIdx.x;
  const int w = tid >> 6, lane = tid & 63;
  const int quad = lane >> 4, nIdx = lane & 15;
  const int dir = blockIdx.x >> 5, wg = blockIdx.x & 31;
  const int rowp = wg * 64 + w * 16 + nIdx;
  const int gate = rowp & 3;
  const int u = rowp >> 2;
  const uint16_t* xg = dir ? xg_b : xg_f;
  const uint16_t* Wrow = WhP + ((size_t)dir * 2048 + rowp) * 512;
  bf8 bfr[16];
  #pragma unroll
  for (int kt = 0; kt < 16; ++kt) bfr[kt] = *(const bf8*)(Wrow + kt * 32 + quad * 8);
  float c[16], h[16];
  int len[16];
  #pragma unroll
  for (int si = 0; si < 16; ++si) { c[si] = 0.f; h[si] = 0.f; }
  #pragma unroll
  for (int mt = 0; mt < 4; ++mt)
    #pragma unroll
    for (int r = 0; r < 4; ++r) len[mt * 4 + r] = lens[mt * 16 + quad * 4 + r];
  int* myctr = ctr + dir * 512;
  uint16_t* hb = hbuf + (size_t)dir * 2 * NB * NH;
  // byte voffset for the staging loads: row (i*4+w), col lane*8  (constant per thread)
  const uint32_t voff = (uint32_t)(w * 512 + lane * 8) * 2;
  // byte voffset base for h stores: (bb*512 + u)*2 with bb varying
  const uint32_t u2 = (uint32_t)u * 2;

  // prefetch xg for step 0
  uint16_t xgp[16];
  {
    const int t0 = dir ? 511 : 0;
    #pragma unroll
    for (int mt = 0; mt < 4; ++mt)
      #pragma unroll
      for (int r = 0; r < 4; ++r) {
        const int bb = mt * 16 + quad * 4 + r;
        xgp[mt * 4 + r] = xg[((size_t)t0 * 64 + bb) * 2048 + rowp];
      }
  }

  for (int s = 0; s < 512; ++s) {
    const int t = dir ? (511 - s) : s;
    f4 acc[4];
    #pragma unroll
    for (int mt = 0; mt < 4; ++mt)
      #pragma unroll
      for (int q = 0; q < 4; ++q) acc[mt][q] = 0.f;
    if (s > 0) {
      if (tid == 0) {
        while (__hip_atomic_load(myctr + (s - 1), __ATOMIC_RELAXED, __HIP_MEMORY_SCOPE_AGENT) < 32)
          __builtin_amdgcn_s_sleep(1);
      }
      __syncthreads();
      // ---- stage h (64x512 bf16) via coherence-point loads, batched MLP ----
      const uint16_t* hr = hb + ((s + 1) & 1) * (NB * NH);
      bf8 tmp[16];
      #pragma unroll
      for (int i = 0; i < 16; ++i) {
        const uint16_t* p = hr + i * 2048;   // uniform saddr; voff = per-thread bytes
        asm volatile("global_load_dwordx4 %0, %1, %2 sc0 sc1"
                     : "=v"(tmp[i]) : "v"(voff), "s"(p) : "memory");
      }
      asm volatile("s_waitcnt vmcnt(0)" ::: "memory");
      #pragma unroll
      for (int i = 0; i < 16; ++i) {
        *(bf8*)&hlds[(i * 4 + w) * 520 + lane * 8] = tmp[i];
      }
      __syncthreads();
      // ---- MFMA from LDS ----
      #pragma unroll
      for (int mt = 0; mt < 4; ++mt) {
        const uint16_t* hrow = &hlds[(mt * 16 + nIdx) * 520 + quad * 8];
        #pragma unroll
        for (int kt = 0; kt < 16; ++kt)
          acc[mt] = __builtin_amdgcn_mfma_f32_16x16x32_bf16(
              *(const bf8*)(hrow + kt * 32), bfr[kt], acc[mt], 0, 0, 0);
      }
    }
    uint16_t* hw = hb + (s & 1) * (NB * NH);
    #pragma unroll
    for (int mt = 0; mt < 4; ++mt) {
      #pragma unroll
      for (int r = 0; r < 4; ++r) {
        const int si = mt * 4 + r;
        const int bb = mt * 16 + quad * 4 + r;
        float g = acc[mt][r] + bf2f(xgp[si]);
        float act;
        if (gate == 2) { float e = __expf(2.f * g); act = 1.f - 2.f / (e + 1.f); }
        else           { act = 1.f / (1.f + __expf(-g)); }
        float a1 = __shfl_xor(act, 1, 64);
        float a2 = __shfl_xor(act, 2, 64);
        float a3 = __shfl_xor(act, 3, 64);
        float vi = (gate == 0) ? act : ((gate == 1) ? a1 : ((gate == 2) ? a2 : a3));
        float vf = (gate == 1) ? act : ((gate == 0) ? a1 : ((gate == 3) ? a2 : a3));
        float vg = (gate == 2) ? act : ((gate == 3) ? a1 : ((gate == 0) ? a2 : a3));
        float vo = (gate == 3) ? act : ((gate == 2) ? a1 : ((gate == 1) ? a2 : a3));
        float cn = vf * c[si] + vi * vg;
        float e2 = __expf(2.f * cn);
        float th = 1.f - 2.f / (e2 + 1.f);
        float hn = vo * th;
        bool valid = (t < len[si]);
        float cnew = valid ? cn : c[si];
        float hnew = valid ? hn : h[si];
        c[si] = cnew; h[si] = hnew;
        if (gate == 1) {
          // write-through h to coherence point (fire & forget; drained pre-add)
          uint32_t vo2 = (uint32_t)bb * 1024 + u2;
          uint32_t data = f2bf(hnew);
          asm volatile("global_store_short %0, %1, %2 sc0 sc1"
                       :: "v"(vo2), "v"(data), "s"(hw) : "memory");
        }
        if (gate == 0) {
          float yv = valid ? hn : 0.f;
          size_t yo = ((size_t)bb * 512 + t) * 1024 + (size_t)dir * 512 + u;
          if (FINAL) __builtin_nontemporal_store(yv, &dout[yo]);
          else       __builtin_nontemporal_store(f2bf(yv), &y0[yo]);
        }
      }
    }
    asm volatile("s_waitcnt vmcnt(0)" ::: "memory");   // h at coherence point
    __syncthreads();                                   // all waves drained
    if (tid == 0) atomicAdd(myctr + s, 1);             // arrive (device-scope RMW)
    // ---- prefetch xg for next step during the spin window ----
    {
      const int sp = (s + 1 < 512) ? (s + 1) : 511;
      const int t2 = dir ? (511 - sp) : sp;
      #pragma unroll
      for (int mt = 0; mt < 4; ++mt)
        #pragma unroll
        for (int r = 0; r < 4; ++r) {
          const int bb = mt * 16 + quad * 4 + r;
          xgp[mt * 4 + r] = xg[((size_t)t2 * 64 + bb) * 2048 + rowp];
        }
    }
  }
  if (gate == 2) {
    const size_t HN = 33554432, CN = 33554432 + 131072;
    int slot = layer * 2 + dir;
    #pragma unroll
    for (int mt = 0; mt < 4; ++mt)
      #pragma unroll
      for (int r = 0; r < 4; ++r) {
        int bb = mt * 16 + quad * 4 + r;
        dout[HN + ((size_t)slot * 64 + bb) * 512 + u] = h[mt * 4 + r];
        dout[CN + ((size_t)slot * 64 + bb) * 512 + u] = c[mt * 4 + r];
      }
  }
}

extern "C" void kernel_launch(void* const* d_in, const int* in_sizes, int n_in,
                              void* d_out, int out_size, void* d_ws, size_t ws_size,
                              hipStream_t stream) {
  (void)in_sizes; (void)n_in; (void)out_size; (void)ws_size;
  const float* x     = (const float*)d_in[0];
  const int*   lens  = (const int*)d_in[1];
  const float* Wi_f0 = (const float*)d_in[2];
  const float* Wh_f0 = (const float*)d_in[3];
  const float* b_f0  = (const float*)d_in[4];
  const float* Wi_b0 = (const float*)d_in[5];
  const float* Wh_b0 = (const float*)d_in[6];
  const float* b_b0  = (const float*)d_in[7];
  const float* Wi_f1 = (const float*)d_in[8];
  const float* Wh_f1 = (const float*)d_in[9];
  const float* b_f1  = (const float*)d_in[10];
  const float* Wi_b1 = (const float*)d_in[11];
  const float* Wh_b1 = (const float*)d_in[12];
  const float* b_b1  = (const float*)d_in[13];
  float* out = (float*)d_out;
  char* ws = (char*)d_ws;

  const size_t CTR = 0;                       // int[2][2][512] = 8 KB
  const size_t BIAS0 = 8192, BIAS1 = 24576;   // fp32 [4096] each
  const size_t HBUF = 40960;                  // bf16 [2][2][64][512] = 256 KB
  const size_t XBF   = 303104;                // bf16 x: 32 MB
  const size_t Y0    = XBF + 33554432;        // bf16 y0 [64][512][1024]: 64 MB
  const size_t WCAT0 = Y0 + 67108864;         // bf16 [4096][512]
  const size_t WCAT1 = WCAT0 + 4194304;       // bf16 [4096][1024]
  const size_t WHP0  = WCAT1 + 8388608;       // bf16 [2][2048][512]
  const size_t WHP1  = WHP0 + 4194304;
  const size_t XGF   = WHP1 + 4194304;        // bf16 [512][64][2048]: 128 MB
  const size_t XGB   = XGF + 134217728;       // 128 MB  (total ~372 MB)

  int* ctr        = (int*)(ws + CTR);
  float* bias0    = (float*)(ws + BIAS0);
  float* bias1    = (float*)(ws + BIAS1);
  uint16_t* hbuf  = (uint16_t*)(ws + HBUF);
  uint16_t* xbf   = (uint16_t*)(ws + XBF);
  uint16_t* y0    = (uint16_t*)(ws + Y0);
  uint16_t* wcat0 = (uint16_t*)(ws + WCAT0);
  uint16_t* wcat1 = (uint16_t*)(ws + WCAT1);
  uint16_t* whp0  = (uint16_t*)(ws + WHP0);
  uint16_t* whp1  = (uint16_t*)(ws + WHP1);
  uint16_t* xgf   = (uint16_t*)(ws + XGF);
  uint16_t* xgb   = (uint16_t*)(ws + XGB);

  hipMemsetAsync(ws + CTR, 0, 8192, stream);
  k_f2bf<<<16384, 256, 0, stream>>>(x, xbf, 4194304);
  k_wperm<<<2048, 256, 0, stream>>>(Wi_f0, wcat0, 512);
  k_wperm<<<2048, 256, 0, stream>>>(Wi_b0, wcat0 + 2048 * 512, 512);
  k_wperm<<<2048, 256, 0, stream>>>(Wi_f1, wcat1, 1024);
  k_wperm<<<2048, 256, 0, stream>>>(Wi_b1, wcat1 + (size_t)2048 * 1024, 1024);
  k_wperm<<<2048, 256, 0, stream>>>(Wh_f0, whp0, 512);
  k_wperm<<<2048, 256, 0, stream>>>(Wh_b0, whp0 + 2048 * 512, 512);
  k_wperm<<<2048, 256, 0, stream>>>(Wh_f1, whp1, 512);
  k_wperm<<<2048, 256, 0, stream>>>(Wh_b1, whp1 + 2048 * 512, 512);
  k_bperm<<<8, 256, 0, stream>>>(b_f0, bias0);
  k_bperm<<<8, 256, 0, stream>>>(b_b0, bias0 + 2048);
  k_bperm<<<8, 256, 0, stream>>>(b_f1, bias1);
  k_bperm<<<8, 256, 0, stream>>>(b_b1, bias1 + 2048);

  k_gemm<512><<<dim3(32, 256), 256, 0, stream>>>(xbf, wcat0, bias0, xgf, xgb);
  k_recur<false><<<64, 256, 0, stream>>>(xgf, xgb, whp0, lens, hbuf, ctr, y0, out, 0);
  k_gemm<1024><<<dim3(32, 256), 256, 0, stream>>>(y0, wcat1, bias1, xgf, xgb);
  k_recur<true><<<64, 256, 0, stream>>>(xgf, xgb, whp1, lens, hbuf, ctr + 1024, y0, out, 1);
}

// Round 4
// 8307.411 us; speedup vs baseline: 3.2200x; 1.0429x over previous
//
#include <hip/hip_runtime.h>
#include <stdint.h>

#define NB 64
#define NT 512
#define NH 512

typedef short bf8 __attribute__((ext_vector_type(8)));   // 8 bf16 vals (4 VGPRs)
typedef float f4  __attribute__((ext_vector_type(4)));

static __device__ __forceinline__ float bf2f(uint16_t u) {
  union { uint32_t i; float f; } v; v.i = ((uint32_t)u) << 16; return v.f;
}
static __device__ __forceinline__ uint16_t f2bf(float f) {
  union { float f; uint32_t i; } v; v.f = f;
  uint32_t r = v.i + 0x7fffu + ((v.i >> 16) & 1u);
  return (uint16_t)(r >> 16);
}

__global__ void k_f2bf(const float* __restrict__ src, uint16_t* __restrict__ dst, int n4) {
  int i = blockIdx.x * 256 + threadIdx.x;
  if (i < n4) {
    float4 v = ((const float4*)src)[i];
    uint16_t* d = dst + (size_t)i * 4;
    d[0] = f2bf(v.x); d[1] = f2bf(v.y); d[2] = f2bf(v.z); d[3] = f2bf(v.w);
  }
}

// rows permuted: row' = u*4+gate  <-  row = gate*512 + u ; fp32 -> bf16
__global__ void k_wperm(const float* __restrict__ src, uint16_t* __restrict__ dst, int K) {
  int rp = blockIdx.x;
  int row = (rp & 3) * NH + (rp >> 2);
  const float* s = src + (size_t)row * K;
  uint16_t* d = dst + (size_t)rp * K;
  for (int k = threadIdx.x; k < K; k += 256) d[k] = f2bf(s[k]);
}

__global__ void k_bperm(const float* __restrict__ src, float* __restrict__ dst) {
  int rp = blockIdx.x * 256 + threadIdx.x;
  if (rp < 2048) {
    int row = (rp & 3) * NH + (rp >> 2);
    dst[rp] = src[row];
  }
}

// C[m=b*T+t][n] = A[m][:] . W[n][:]  + bias[n], written bf16 to xg[t][b][n&2047]
template<int K>
__global__ __launch_bounds__(256, 2)
void k_gemm(const uint16_t* __restrict__ A, const uint16_t* __restrict__ W,
            const float* __restrict__ bias,
            uint16_t* __restrict__ xg_f, uint16_t* __restrict__ xg_b) {
  __shared__ __align__(16) uint16_t lds[2][2][8][512];   // 32 KB
  const int tid = threadIdx.x;
  const int w = tid >> 6, lane = tid & 63;
  const int quad = lane >> 4, nIdx = lane & 15;
  const int bn = blockIdx.x, bm = blockIdx.y;
  const int wm = w >> 1, wn = w & 1;
  constexpr int KS = K / 32;

  f4 acc[4][4];
  #pragma unroll
  for (int i = 0; i < 4; ++i)
    #pragma unroll
    for (int j = 0; j < 4; ++j)
      #pragma unroll
      for (int q = 0; q < 4; ++q) acc[i][j][q] = 0.f;

  const size_t arow0 = (size_t)(bm * 128 + nIdx) * K + quad * 8;
  const size_t brow0 = (size_t)(bn * 128 + nIdx) * K + quad * 8;

  #pragma unroll
  for (int cc = 0; cc < 2; ++cc) {
    int mt = w + cc * 4;
    bf8 va = *(const bf8*)(A + arow0 + (size_t)mt * 16 * K);
    bf8 vb = *(const bf8*)(W + brow0 + (size_t)mt * 16 * K);
    *(bf8*)&lds[0][0][mt][lane * 8] = va;
    *(bf8*)&lds[0][1][mt][lane * 8] = vb;
  }
  for (int ks = 0; ks < KS; ++ks) {
    __syncthreads();
    bf8 va[2], vb[2];
    const bool pre = (ks + 1 < KS);
    if (pre) {
      #pragma unroll
      for (int cc = 0; cc < 2; ++cc) {
        int mt = w + cc * 4;
        va[cc] = *(const bf8*)(A + arow0 + (size_t)mt * 16 * K + (ks + 1) * 32);
        vb[cc] = *(const bf8*)(W + brow0 + (size_t)mt * 16 * K + (ks + 1) * 32);
      }
    }
    const int buf = ks & 1;
    bf8 af[4], bg[4];
    #pragma unroll
    for (int i = 0; i < 4; ++i) af[i] = *(const bf8*)&lds[buf][0][wm * 4 + i][lane * 8];
    #pragma unroll
    for (int j = 0; j < 4; ++j) bg[j] = *(const bf8*)&lds[buf][1][wn * 4 + j][lane * 8];
    #pragma unroll
    for (int i = 0; i < 4; ++i)
      #pragma unroll
      for (int j = 0; j < 4; ++j)
        acc[i][j] = __builtin_amdgcn_mfma_f32_16x16x32_bf16(af[i], bg[j], acc[i][j], 0, 0, 0);
    if (pre) {
      #pragma unroll
      for (int cc = 0; cc < 2; ++cc) {
        int mt = w + cc * 4;
        *(bf8*)&lds[buf ^ 1][0][mt][lane * 8] = va[cc];
        *(bf8*)&lds[buf ^ 1][1][mt][lane * 8] = vb[cc];
      }
    }
  }
  #pragma unroll
  for (int i = 0; i < 4; ++i) {
    int mbase = bm * 128 + (wm * 4 + i) * 16 + quad * 4;
    #pragma unroll
    for (int r = 0; r < 4; ++r) {
      int mm = mbase + r;
      int bb = mm >> 9, tt = mm & 511;
      size_t rowoff = ((size_t)tt * 64 + bb) * 2048;
      #pragma unroll
      for (int j = 0; j < 4; ++j) {
        int n = bn * 128 + (wn * 4 + j) * 16 + nIdx;
        float v = acc[i][j][r] + bias[n];
        uint16_t* dst = (n < 2048) ? xg_f : xg_b;
        dst[rowoff + (n & 2047)] = f2bf(v);
      }
    }
  }
}

// Persistent recurrence. grid = 64 blocks: dir = blk>>5, wg = blk&31 owns
// rows' [wg*64, wg*64+64). Wave w: rows' wg*64+w*16+nIdx, all 64 batches.
// Sync per step: producers ds-transpose h -> 8x global_store_dwordx4 sc0 sc1
// per WG -> vmcnt drain -> flag[s][wg]=s+1 (plain coherent store, no RMW).
// Consumers: wave0 polls all 32 flags in parallel (signed >=, poison-safe),
// then 16x global_load_dwordx4 sc0 sc1 staging into padded LDS, MFMA, gates.
// y-stores and xg prefetch sit AFTER the flag publish (off critical path).
template<bool FINAL>
__global__ __launch_bounds__(256, 1)
void k_recur(const uint16_t* __restrict__ xg_f, const uint16_t* __restrict__ xg_b,
             const uint16_t* __restrict__ WhP, const int* __restrict__ lens,
             uint16_t* __restrict__ hbuf, int* __restrict__ flags,
             uint16_t* __restrict__ y0, float* __restrict__ dout, int layer) {
  __shared__ __align__(16) uint16_t hlds[64 * 520];   // staging: 64 x (512+8) u16
  __shared__ __align__(16) uint16_t hT[64 * 40];      // h transpose tile: rows bb, stride 40
  const int tid = threadIdx.x;
  const int w = tid >> 6, lane = tid & 63;
  const int quad = lane >> 4, nIdx = lane & 15;
  const int dir = blockIdx.x >> 5, wg = blockIdx.x & 31;
  const int rowp = wg * 64 + w * 16 + nIdx;
  const int gate = rowp & 3;
  const int u = rowp >> 2;
  const int u_local = u - wg * 16;                    // 0..15 within this WG's tile
  const uint16_t* xg = dir ? xg_b : xg_f;
  const uint16_t* Wrow = WhP + ((size_t)dir * 2048 + rowp) * 512;
  bf8 bfr[16];
  #pragma unroll
  for (int kt = 0; kt < 16; ++kt) bfr[kt] = *(const bf8*)(Wrow + kt * 32 + quad * 8);
  float c[16], h[16];
  int len[16];
  #pragma unroll
  for (int si = 0; si < 16; ++si) { c[si] = 0.f; h[si] = 0.f; }
  #pragma unroll
  for (int mt = 0; mt < 4; ++mt)
    #pragma unroll
    for (int r = 0; r < 4; ++r) len[mt * 4 + r] = lens[mt * 16 + quad * 4 + r];
  int* flg = flags + dir * 512 * 32;
  uint16_t* hb = hbuf + (size_t)dir * 2 * NB * NH;
  const uint32_t voff = (uint32_t)(w * 512 + lane * 8) * 2;   // staging-load byte offset

  // prefetch xg for step 0
  uint16_t xgp[16];
  {
    const int t0 = dir ? 511 : 0;
    #pragma unroll
    for (int mt = 0; mt < 4; ++mt)
      #pragma unroll
      for (int r = 0; r < 4; ++r) {
        const int bb = mt * 16 + quad * 4 + r;
        xgp[mt * 4 + r] = xg[((size_t)t0 * 64 + bb) * 2048 + rowp];
      }
  }

  for (int s = 0; s < 512; ++s) {
    const int t = dir ? (511 - s) : s;
    f4 acc[4];
    #pragma unroll
    for (int mt = 0; mt < 4; ++mt)
      #pragma unroll
      for (int q = 0; q < 4; ++q) acc[mt][q] = 0.f;
    if (s > 0) {
      if (w == 0) {
        const int* fp = flg + (s - 1) * 32 + (lane & 31);
        while (true) {
          int v = __hip_atomic_load(fp, __ATOMIC_RELAXED, __HIP_MEMORY_SCOPE_AGENT);
          if (__all(v >= s)) break;     // poison 0xAAAAAAAA is negative -> safe
          __builtin_amdgcn_s_sleep(1);
        }
      }
      __syncthreads();
      // ---- stage h (64x512 bf16) via coherence-point loads, batched MLP ----
      const uint16_t* hr = hb + ((s + 1) & 1) * (NB * NH);
      bf8 tmp[16];
      #pragma unroll
      for (int i = 0; i < 16; ++i) {
        const uint16_t* p = hr + i * 2048;   // uniform saddr; voff = per-thread bytes
        asm volatile("global_load_dwordx4 %0, %1, %2 sc0 sc1"
                     : "=v"(tmp[i]) : "v"(voff), "s"(p) : "memory");
      }
      asm volatile("s_waitcnt vmcnt(0)" ::: "memory");
      #pragma unroll
      for (int i = 0; i < 16; ++i) {
        *(bf8*)&hlds[(i * 4 + w) * 520 + lane * 8] = tmp[i];
      }
      __syncthreads();
      // ---- MFMA from LDS ----
      #pragma unroll
      for (int mt = 0; mt < 4; ++mt) {
        const uint16_t* hrow = &hlds[(mt * 16 + nIdx) * 520 + quad * 8];
        #pragma unroll
        for (int kt = 0; kt < 16; ++kt)
          acc[mt] = __builtin_amdgcn_mfma_f32_16x16x32_bf16(
              *(const bf8*)(hrow + kt * 32), bfr[kt], acc[mt], 0, 0, 0);
      }
    }
    // ---- gates ----
    float yv[16];
    #pragma unroll
    for (int mt = 0; mt < 4; ++mt) {
      #pragma unroll
      for (int r = 0; r < 4; ++r) {
        const int si = mt * 4 + r;
        const int bb = mt * 16 + quad * 4 + r;
        float g = acc[mt][r] + bf2f(xgp[si]);
        float act;
        if (gate == 2) { float e = __expf(2.f * g); act = 1.f - 2.f / (e + 1.f); }
        else           { act = 1.f / (1.f + __expf(-g)); }
        float a1 = __shfl_xor(act, 1, 64);
        float a2 = __shfl_xor(act, 2, 64);
        float a3 = __shfl_xor(act, 3, 64);
        float vi = (gate == 0) ? act : ((gate == 1) ? a1 : ((gate == 2) ? a2 : a3));
        float vf = (gate == 1) ? act : ((gate == 0) ? a1 : ((gate == 3) ? a2 : a3));
        float vg = (gate == 2) ? act : ((gate == 3) ? a1 : ((gate == 0) ? a2 : a3));
        float vo = (gate == 3) ? act : ((gate == 2) ? a1 : ((gate == 1) ? a2 : a3));
        float cn = vf * c[si] + vi * vg;
        float e2 = __expf(2.f * cn);
        float th = 1.f - 2.f / (e2 + 1.f);
        float hn = vo * th;
        bool valid = (t < len[si]);
        float cnew = valid ? cn : c[si];
        float hnew = valid ? hn : h[si];
        c[si] = cnew; h[si] = hnew;
        yv[si] = valid ? hn : 0.f;
        if (gate == 1) hT[bb * 40 + u_local] = f2bf(hnew);   // LDS transpose
      }
    }
    __syncthreads();   // hT complete (all waves)
    // ---- coalesced h publish: threads 0..127 store 16B each (2 KB total) ----
    if (tid < 128) {
      uint16_t* hw = hb + (s & 1) * (NB * NH);
      const int bb = tid >> 1, half = tid & 1;
      bf8 hv = *(const bf8*)&hT[bb * 40 + half * 8];
      uint32_t vo2 = (uint32_t)bb * 1024 + (uint32_t)wg * 32 + (uint32_t)half * 16;
      asm volatile("global_store_dwordx4 %0, %1, %2 sc0 sc1"
                   :: "v"(vo2), "v"(hv), "s"(hw) : "memory");
      asm volatile("s_waitcnt vmcnt(0)" ::: "memory");   // h acked at coherence point
    }
    __syncthreads();   // all h stores acked
    if (tid == 0) {
      uint32_t fo = (uint32_t)(s * 32 + wg) * 4;
      uint32_t fv = (uint32_t)(s + 1);
      asm volatile("global_store_dword %0, %1, %2 sc0 sc1"
                   :: "v"(fo), "v"(fv), "s"(flg) : "memory");
    }
    // ---- off-critical-path: y stores + xg prefetch (overlap the spin) ----
    if (gate == 0) {
      #pragma unroll
      for (int mt = 0; mt < 4; ++mt)
        #pragma unroll
        for (int r = 0; r < 4; ++r) {
          const int bb = mt * 16 + quad * 4 + r;
          size_t yo = ((size_t)bb * 512 + t) * 1024 + (size_t)dir * 512 + u;
          if (FINAL) __builtin_nontemporal_store(yv[mt * 4 + r], &dout[yo]);
          else       __builtin_nontemporal_store(f2bf(yv[mt * 4 + r]), &y0[yo]);
        }
    }
    {
      const int sp = (s + 1 < 512) ? (s + 1) : 511;
      const int t2 = dir ? (511 - sp) : sp;
      #pragma unroll
      for (int mt = 0; mt < 4; ++mt)
        #pragma unroll
        for (int r = 0; r < 4; ++r) {
          const int bb = mt * 16 + quad * 4 + r;
          xgp[mt * 4 + r] = xg[((size_t)t2 * 64 + bb) * 2048 + rowp];
        }
    }
  }
  if (gate == 2) {
    const size_t HN = 33554432, CN = 33554432 + 131072;
    int slot = layer * 2 + dir;
    #pragma unroll
    for (int mt = 0; mt < 4; ++mt)
      #pragma unroll
      for (int r = 0; r < 4; ++r) {
        int bb = mt * 16 + quad * 4 + r;
        dout[HN + ((size_t)slot * 64 + bb) * 512 + u] = h[mt * 4 + r];
        dout[CN + ((size_t)slot * 64 + bb) * 512 + u] = c[mt * 4 + r];
      }
  }
}

extern "C" void kernel_launch(void* const* d_in, const int* in_sizes, int n_in,
                              void* d_out, int out_size, void* d_ws, size_t ws_size,
                              hipStream_t stream) {
  (void)in_sizes; (void)n_in; (void)out_size; (void)ws_size;
  const float* x     = (const float*)d_in[0];
  const int*   lens  = (const int*)d_in[1];
  const float* Wi_f0 = (const float*)d_in[2];
  const float* Wh_f0 = (const float*)d_in[3];
  const float* b_f0  = (const float*)d_in[4];
  const float* Wi_b0 = (const float*)d_in[5];
  const float* Wh_b0 = (const float*)d_in[6];
  const float* b_b0  = (const float*)d_in[7];
  const float* Wi_f1 = (const float*)d_in[8];
  const float* Wh_f1 = (const float*)d_in[9];
  const float* b_f1  = (const float*)d_in[10];
  const float* Wi_b1 = (const float*)d_in[11];
  const float* Wh_b1 = (const float*)d_in[12];
  const float* b_b1  = (const float*)d_in[13];
  float* out = (float*)d_out;
  char* ws = (char*)d_ws;

  const size_t BIAS0 = 8192, BIAS1 = 24576;   // fp32 [4096] each
  const size_t HBUF = 40960;                  // bf16 [2][2][64][512] = 256 KB
  const size_t XBF   = 303104;                // bf16 x: 32 MB
  const size_t Y0    = XBF + 33554432;        // bf16 y0 [64][512][1024]: 64 MB
  const size_t WCAT0 = Y0 + 67108864;         // bf16 [4096][512]
  const size_t WCAT1 = WCAT0 + 4194304;       // bf16 [4096][1024]
  const size_t WHP0  = WCAT1 + 8388608;       // bf16 [2][2048][512]
  const size_t WHP1  = WHP0 + 4194304;
  const size_t XGF   = WHP1 + 4194304;        // bf16 [512][64][2048]: 128 MB
  const size_t XGB   = XGF + 134217728;       // 128 MB
  const size_t FLAGS = XGB + 134217728;       // int[2 layers][2 dirs][512][32] = 256 KB

  float* bias0    = (float*)(ws + BIAS0);
  float* bias1    = (float*)(ws + BIAS1);
  uint16_t* hbuf  = (uint16_t*)(ws + HBUF);
  uint16_t* xbf   = (uint16_t*)(ws + XBF);
  uint16_t* y0    = (uint16_t*)(ws + Y0);
  uint16_t* wcat0 = (uint16_t*)(ws + WCAT0);
  uint16_t* wcat1 = (uint16_t*)(ws + WCAT1);
  uint16_t* whp0  = (uint16_t*)(ws + WHP0);
  uint16_t* whp1  = (uint16_t*)(ws + WHP1);
  uint16_t* xgf   = (uint16_t*)(ws + XGF);
  uint16_t* xgb   = (uint16_t*)(ws + XGB);
  int* flags      = (int*)(ws + FLAGS);

  k_f2bf<<<16384, 256, 0, stream>>>(x, xbf, 4194304);
  k_wperm<<<2048, 256, 0, stream>>>(Wi_f0, wcat0, 512);
  k_wperm<<<2048, 256, 0, stream>>>(Wi_b0, wcat0 + 2048 * 512, 512);
  k_wperm<<<2048, 256, 0, stream>>>(Wi_f1, wcat1, 1024);
  k_wperm<<<2048, 256, 0, stream>>>(Wi_b1, wcat1 + (size_t)2048 * 1024, 1024);
  k_wperm<<<2048, 256, 0, stream>>>(Wh_f0, whp0, 512);
  k_wperm<<<2048, 256, 0, stream>>>(Wh_b0, whp0 + 2048 * 512, 512);
  k_wperm<<<2048, 256, 0, stream>>>(Wh_f1, whp1, 512);
  k_wperm<<<2048, 256, 0, stream>>>(Wh_b1, whp1 + 2048 * 512, 512);
  k_bperm<<<8, 256, 0, stream>>>(b_f0, bias0);
  k_bperm<<<8, 256, 0, stream>>>(b_b0, bias0 + 2048);
  k_bperm<<<8, 256, 0, stream>>>(b_f1, bias1);
  k_bperm<<<8, 256, 0, stream>>>(b_b1, bias1 + 2048);

  k_gemm<512><<<dim3(32, 256), 256, 0, stream>>>(xbf, wcat0, bias0, xgf, xgb);
  k_recur<false><<<64, 256, 0, stream>>>(xgf, xgb, whp0, lens, hbuf, flags, y0, out, 0);
  k_gemm<1024><<<dim3(32, 256), 256, 0, stream>>>(y0, wcat1, bias1, xgf, xgb);
  k_recur<true><<<64, 256, 0, stream>>>(xgf, xgb, whp1, lens, hbuf, flags + 2 * 512 * 32, y0, out, 1);
}